// Round 13
// baseline (376.771 us; speedup 1.0000x reference)
//
#include <hip/hip_runtime.h>
#include <stdint.h>

// MultiHeadAttention: B=2, S=2048, D=1024, H=16, dk=64
// d_in (fp32): Q,K,V, mask(int32), Wq,bq,Wk,bk,Wv,bv,Wo,bo
// d_out (FP32): out [2,2048,1024] then attn [2,16,2048,2048], concatenated.
// R13: attn_fused sync ported to counted-vmcnt + raw s_barrier (T4):
//      stage loads stay in flight across barriers (vmcnt(5)/vmcnt(1), never 0
//      in the main loop). Everything else identical to R12.

typedef __attribute__((ext_vector_type(8))) short bf16x8;
typedef __attribute__((ext_vector_type(4))) float f32x4;
typedef unsigned long long u64;

#define MFMA16(a, b, c) __builtin_amdgcn_mfma_f32_16x16x32_bf16((a), (b), (c), 0, 0, 0)

#define GLDS16(g, l)                                                   \
  __builtin_amdgcn_global_load_lds(                                    \
      (const __attribute__((address_space(1))) unsigned int*)(g),      \
      (__attribute__((address_space(3))) unsigned int*)(l), 16, 0, 0)

__device__ __forceinline__ float bf2f(short s) {
  union { float f; unsigned u; } x;
  x.u = ((unsigned)(unsigned short)s) << 16;
  return x.f;
}
__device__ __forceinline__ short f2bf(float f) {  // RTNE
  union { float f; unsigned u; } x;
  x.f = f;
  unsigned r = x.u + 0x7fffu + ((x.u >> 16) & 1u);
  return (short)(r >> 16);
}
__device__ __forceinline__ bf16x8 pack8(float4 a, float4 b) {
  union { short s[8]; bf16x8 v; } u;
  u.s[0] = f2bf(a.x); u.s[1] = f2bf(a.y); u.s[2] = f2bf(a.z); u.s[3] = f2bf(a.w);
  u.s[4] = f2bf(b.x); u.s[5] = f2bf(b.y); u.s[6] = f2bf(b.z); u.s[7] = f2bf(b.w);
  return u.v;
}

// ---------------- diagnostic sentinel --------------------------------------
__global__ __launch_bounds__(256) void sentinel_fill(float* __restrict__ out,
                                                     float v, int n) {
  int i = blockIdx.x * 256 + threadIdx.x;
  if (i < n) out[i] = v;
}

// ---------------- mask bit-pack: [B,S,S] int32 -> [B,S,S/64] u64 ----------
__global__ __launch_bounds__(256) void pack_mask(const int* __restrict__ m,
                                                 u64* __restrict__ p) {
  long idx = (long)blockIdx.x * 256 + threadIdx.x;
  u64 b = __ballot(m[idx] != 0);
  if ((threadIdx.x & 63) == 0) p[idx >> 6] = b;
}

// ------------- merged QKV projection: 3 GEMMs in one launch ----------------
struct QkvPtrs {
  const float *A0, *A1, *A2;
  const float *W0, *W1, *W2;
  const float *c0, *c1, *c2;
  short *o0, *o1, *o2;
};
__global__ __launch_bounds__(256) void gemm_qkv(QkvPtrs p) {
  __shared__ short As[128 * 32];
  __shared__ short Bs[128 * 32];
  const int z = blockIdx.z;
  const float* Af = z == 0 ? p.A0 : (z == 1 ? p.A1 : p.A2);
  const float* W = z == 0 ? p.W0 : (z == 1 ? p.W1 : p.W2);
  const float* bias = z == 0 ? p.c0 : (z == 1 ? p.c1 : p.c2);
  short* outs = z == 0 ? p.o0 : (z == 1 ? p.o1 : p.o2);

  const int tid = threadIdx.x;
  const int lane = tid & 63;
  const int wid = tid >> 6;
  const int wr = wid >> 1, wc = wid & 1;
  const int m0 = blockIdx.x * 128;
  const int n0 = blockIdx.y * 128;

  const int srow = tid >> 1;
  const int scol = (tid & 1) << 4;
  const long aoff = (long)(m0 + srow) * 1024 + scol;
  const float* Wg = W + (long)(n0 + srow) * 1024 + scol;
  short* sA = As + srow * 32 + scol;
  short* sB = Bs + srow * 32 + scol;

  f32x4 acc[4][4] = {};
  const int fr = lane & 15;
  const int fc = (lane >> 4) << 3;

  for (int k0 = 0; k0 < 1024; k0 += 32) {
    __syncthreads();
    float4 x0 = *(const float4*)(Af + aoff + k0);
    float4 x1 = *(const float4*)(Af + aoff + k0 + 4);
    float4 x2 = *(const float4*)(Af + aoff + k0 + 8);
    float4 x3 = *(const float4*)(Af + aoff + k0 + 12);
    float4 w0 = *(const float4*)(Wg + k0);
    float4 w1 = *(const float4*)(Wg + k0 + 4);
    float4 w2 = *(const float4*)(Wg + k0 + 8);
    float4 w3 = *(const float4*)(Wg + k0 + 12);
    *(bf16x8*)sA = pack8(x0, x1);
    *(bf16x8*)(sA + 8) = pack8(x2, x3);
    *(bf16x8*)sB = pack8(w0, w1);
    *(bf16x8*)(sB + 8) = pack8(w2, w3);
    __syncthreads();
    bf16x8 a[4], b[4];
#pragma unroll
    for (int i = 0; i < 4; ++i)
      a[i] = *(const bf16x8*)&As[(wr * 64 + i * 16 + fr) * 32 + fc];
#pragma unroll
    for (int i = 0; i < 4; ++i)
      b[i] = *(const bf16x8*)&Bs[(wc * 64 + i * 16 + fr) * 32 + fc];
#pragma unroll
    for (int i = 0; i < 4; ++i)
#pragma unroll
      for (int j = 0; j < 4; ++j)
        acc[i][j] = MFMA16(a[i], b[j], acc[i][j]);
  }

#pragma unroll
  for (int i = 0; i < 4; ++i) {
    const int row0 = m0 + wr * 64 + i * 16 + (lane >> 4) * 4;
#pragma unroll
    for (int j = 0; j < 4; ++j) {
      const int col = n0 + wc * 64 + j * 16 + fr;
      const float bv = bias[col];
      const int h = col >> 6, dd = col & 63;
      if (z != 2) {
#pragma unroll
        for (int r = 0; r < 4; ++r) {
          const int m = row0 + r;
          const long o = (((long)(m >> 11) * 16 + h) * 2048 + (m & 2047)) * 64 + dd;
          outs[o] = f2bf(acc[i][j][r] + bv);
        }
      } else {
        const long o = (((long)(row0 >> 11) * 16 + h) * 64 + dd) * 2048 + (row0 & 2047);
        union { unsigned short us[4]; uint2 v; } pk;
#pragma unroll
        for (int r = 0; r < 4; ++r) pk.us[r] = (unsigned short)f2bf(acc[i][j][r] + bv);
        *(uint2*)&outs[o] = pk.v;
      }
    }
  }
}

// ---------------- final GEMM: out = ctx(bf16) @ Wo^T + bo (fp32 out) -------
__global__ __launch_bounds__(256) void gemm_out(const short* __restrict__ Ab,
                                                const float* __restrict__ W,
                                                const float* __restrict__ bias,
                                                float* __restrict__ outf) {
  __shared__ short As[128 * 32];
  __shared__ short Bs[128 * 32];
  const int tid = threadIdx.x;
  const int lane = tid & 63;
  const int wid = tid >> 6;
  const int wr = wid >> 1, wc = wid & 1;
  const int m0 = blockIdx.x * 128;
  const int n0 = blockIdx.y * 128;

  const int srow = tid >> 1;
  const int scol = (tid & 1) << 4;
  const long aoff = (long)(m0 + srow) * 1024 + scol;
  const float* Wg = W + (long)(n0 + srow) * 1024 + scol;
  short* sA = As + srow * 32 + scol;
  short* sB = Bs + srow * 32 + scol;

  f32x4 acc[4][4] = {};
  const int fr = lane & 15;
  const int fc = (lane >> 4) << 3;

  for (int k0 = 0; k0 < 1024; k0 += 32) {
    __syncthreads();
    bf16x8 va0 = *(const bf16x8*)(Ab + aoff + k0);
    bf16x8 va1 = *(const bf16x8*)(Ab + aoff + k0 + 8);
    float4 w0 = *(const float4*)(Wg + k0);
    float4 w1 = *(const float4*)(Wg + k0 + 4);
    float4 w2 = *(const float4*)(Wg + k0 + 8);
    float4 w3 = *(const float4*)(Wg + k0 + 12);
    *(bf16x8*)sA = va0;
    *(bf16x8*)(sA + 8) = va1;
    *(bf16x8*)sB = pack8(w0, w1);
    *(bf16x8*)(sB + 8) = pack8(w2, w3);
    __syncthreads();
    bf16x8 a[4], b[4];
#pragma unroll
    for (int i = 0; i < 4; ++i)
      a[i] = *(const bf16x8*)&As[(wr * 64 + i * 16 + fr) * 32 + fc];
#pragma unroll
    for (int i = 0; i < 4; ++i)
      b[i] = *(const bf16x8*)&Bs[(wc * 64 + i * 16 + fr) * 32 + fc];
#pragma unroll
    for (int i = 0; i < 4; ++i)
#pragma unroll
      for (int j = 0; j < 4; ++j)
        acc[i][j] = MFMA16(a[i], b[j], acc[i][j]);
  }

#pragma unroll
  for (int i = 0; i < 4; ++i) {
    const int row0 = m0 + wr * 64 + i * 16 + (lane >> 4) * 4;
#pragma unroll
    for (int j = 0; j < 4; ++j) {
      const int col = n0 + wc * 64 + j * 16 + fr;
      const float bv = bias[col];
#pragma unroll
      for (int r = 0; r < 4; ++r)
        outf[(long)(row0 + r) * 1024 + col] = acc[i][j][r] + bv;
    }
  }
}

// ------------- fused attention: counted-vmcnt pipeline (T4) ----------------
// 16 q-rows/wave, 64 rows/block; grid (32 bh, 32 qt); LDS 40KB, 4 blocks/CU.
// Per iter: STAGE(kt+1) + mask(kt+1) -> compute(kt) -> WB(kt) stores ->
// s_waitcnt vmcnt(5) [stage retired; mask+stores in flight] -> raw s_barrier.
__global__ __launch_bounds__(256) void attn_fused(
    const short* __restrict__ qw, const short* __restrict__ kw,
    const short* __restrict__ vtw, const u64* __restrict__ pm,
    float* __restrict__ attn, short* __restrict__ ctx) {
  __shared__ short Ks[2][4096];   // [64 k][64 d] bf16, swizzled
  __shared__ short Vs[2][4096];   // [64 d][64 k] bf16, swizzled
  __shared__ short P[4][1024];    // per-wave [16 r][64 c], XOR-swizzled
  const int tid = threadIdx.x;
  const int lane = tid & 63;
  const int wid = tid >> 6;
  const int bh = blockIdx.x;
  const int mb = bh & 1;  // torch tile quirk: mask batch = (b*H+h)%B
  const int q0 = blockIdx.y * 64 + wid * 16;
  const int fr = lane & 15;
  const int fg = lane >> 4;
  short* Pw = P[wid];

  bf16x8 aq[2];
  {
    const short* qb = qw + ((long)bh * 2048 + q0 + fr) * 64 + fg * 8;
    aq[0] = *(const bf16x8*)qb;
    aq[1] = *(const bf16x8*)(qb + 32);
  }

  const u64* mbase = pm + ((long)mb * 2048 + q0) * 32;
  const short* kbase = kw + (long)bh * 2048 * 64;
  const short* vbase = vtw + (long)bh * 64 * 2048;
  const long arow = (long)bh * 2048 + q0;

  const int sidx0 = tid;
  const int sidx1 = 256 + tid;
  const int sr0 = sidx0 >> 3, ss0 = (sidx0 ^ sr0) & 7;
  const int sr1 = sidx1 >> 3, ss1 = (sidx1 ^ sr1) & 7;
  short* ldst0 = &Ks[0][0] + (long)(wid * 64) * 8;
  short* ldst1 = &Ks[0][0] + (long)(256 + wid * 64) * 8;
  const long kofs = (long)(&Vs[0][0] - &Ks[0][0]);

#define STAGE_K(buf, kt)                                              \
  {                                                                   \
    const short* s_ = kbase + (long)((kt) * 64) * 64;                 \
    GLDS16(s_ + sr0 * 64 + ss0 * 8, ldst0 + (buf) * 4096);            \
    GLDS16(s_ + sr1 * 64 + ss1 * 8, ldst1 + (buf) * 4096);            \
  }
#define STAGE_V(buf, kt)                                              \
  {                                                                   \
    const short* s_ = vbase + (kt) * 64;                              \
    GLDS16(s_ + (long)sr0 * 2048 + ss0 * 8, ldst0 + kofs + (buf) * 4096); \
    GLDS16(s_ + (long)sr1 * 2048 + ss1 * 8, ldst1 + kofs + (buf) * 4096); \
  }
#define SWZ(row, slot) (((row) << 6) + ((((slot) ^ ((row) & 7))) << 3))
#define PADDR(row, col) \
  (((row) << 6) + (((((col) >> 3) ^ ((row) & 7))) << 3) + ((col) & 7))
#define WRITEBACK(kt)                                                 \
  {                                                                   \
    _Pragma("unroll") for (int c = 0; c < 4; ++c) {                   \
      const int idx = c * 64 + lane;                                  \
      const int row = idx >> 4;                                       \
      const int col = (idx & 15) * 4;                                 \
      union { uint2 w; short s[4]; } v4;                              \
      v4.w = *(const uint2*)&Pw[PADDR(row, col)];                     \
      float4 f;                                                       \
      f.x = bf2f(v4.s[0]); f.y = bf2f(v4.s[1]);                       \
      f.z = bf2f(v4.s[2]); f.w = bf2f(v4.s[3]);                       \
      *(float4*)&attn[(arow + row) * 2048 + (kt) * 64 + col] = f;     \
    }                                                                 \
  }
#define WAITBAR(N)                                                    \
  {                                                                   \
    asm volatile("s_waitcnt vmcnt(" #N ")" ::: "memory");             \
    __builtin_amdgcn_sched_barrier(0);                                \
    __builtin_amdgcn_s_barrier();                                     \
    __builtin_amdgcn_sched_barrier(0);                                \
  }

  // ---- phase 1: denominator (swapped QK^T; lane owns q-row q0+fr) ---------
  float rs = 0.f;
  STAGE_K(0, 0);
  u64 mrow = mbase[fr * 32 + 0];
  WAITBAR(1)  // 2 stage loads retired; mask load may remain in flight
  int cur = 0;
  for (int kt = 0; kt < 32; ++kt) {
    u64 mrow_next = 0;
    if (kt < 31) {
      STAGE_K(cur ^ 1, kt + 1);
      mrow_next = mbase[fr * 32 + kt + 1];
    }
#pragma unroll
    for (int ni = 0; ni < 4; ++ni) {
      const int R = ni * 16 + fr;
      bf16x8 b0 = *(const bf16x8*)&Ks[cur][SWZ(R, fg)];
      bf16x8 b1 = *(const bf16x8*)&Ks[cur][SWZ(R, 4 + fg)];
      const int kb0 = ni * 16 + fg * 4;
      f32x4 s = {0.f, 0.f, 0.f, 0.f};
      s = MFMA16(b0, aq[0], s);
      s = MFMA16(b1, aq[1], s);
#pragma unroll
      for (int r = 0; r < 4; ++r)
        if ((mrow >> (kb0 + r)) & 1ULL) rs += __expf(s[r] * 0.125f);
    }
    if (kt < 31) {
      WAITBAR(1)  // queue: 2 stage + mask -> stage retired
      cur ^= 1;
      mrow = mrow_next;
    }
  }
  float il;
  {
    float v = rs;
    v += __shfl_xor(v, 16);
    v += __shfl_xor(v, 32);
    il = 1.0f / v;
  }
  __builtin_amdgcn_s_barrier();  // all waves done with phase-1 buffers

  // ---- phase 2: p -> attn + ctx += P@V (counted-vmcnt pipeline) -----------
  f32x4 cacc[4] = {};
  STAGE_K(0, 0);
  STAGE_V(0, 0);
  mrow = mbase[fr * 32 + 0];
  WAITBAR(1)  // 4 stage loads retired; mask in flight
  cur = 0;
  for (int kt = 0; kt < 32; ++kt) {
    u64 mrow_next = 0;
    if (kt < 31) {
      STAGE_K(cur ^ 1, kt + 1);
      STAGE_V(cur ^ 1, kt + 1);
      mrow_next = mbase[fr * 32 + kt + 1];
    }

#pragma unroll
    for (int ni = 0; ni < 4; ++ni) {
      const int R = ni * 16 + fr;
      bf16x8 b0 = *(const bf16x8*)&Ks[cur][SWZ(R, fg)];
      bf16x8 b1 = *(const bf16x8*)&Ks[cur][SWZ(R, 4 + fg)];
      const int kb0 = ni * 16 + fg * 4;
      f32x4 s = {0.f, 0.f, 0.f, 0.f};
      s = MFMA16(b0, aq[0], s);
      s = MFMA16(b1, aq[1], s);
      union { unsigned short us[4]; uint2 v; } pk;
#pragma unroll
      for (int r = 0; r < 4; ++r) {
        float p = ((mrow >> (kb0 + r)) & 1ULL) ? __expf(s[r] * 0.125f) * il
                                               : 0.0f;
        pk.us[r] = (unsigned short)f2bf(p);
      }
      *(uint2*)&Pw[PADDR(fr, kb0)] = pk.v;
    }

    // ctx += P(16x64) @ V(64x64)   (same-wave LDS dep; ds ops in-order)
#pragma unroll
    for (int ks = 0; ks < 2; ++ks) {
      bf16x8 pa = *(const bf16x8*)&Pw[PADDR(fr, ks * 32 + fg * 8)];
#pragma unroll
      for (int ni = 0; ni < 4; ++ni) {
        const int R = ni * 16 + fr;
        bf16x8 bv = *(const bf16x8*)&Vs[cur][SWZ(R, ks * 4 + fg)];
        cacc[ni] = MFMA16(pa, bv, cacc[ni]);
      }
    }

    WRITEBACK(kt);  // stores issue late; allowed to stay in flight

    if (kt < 31) {
      WAITBAR(5)  // queue: [old stores]+4 stage+mask+4 new stores ->
                  // stage retired, mask + new stores in flight
      cur ^= 1;
      mrow = mrow_next;
    }
  }

  // ctx: [B,S,D] row-major (bf16) for the final GEMM
  const int b_ = bh >> 4, h_ = bh & 15;
#pragma unroll
  for (int ni = 0; ni < 4; ++ni)
#pragma unroll
    for (int r = 0; r < 4; ++r)
      ctx[((long)b_ * 2048 + q0 + fg * 4 + r) * 1024 + h_ * 64 + ni * 16 + fr] =
          f2bf(cacc[ni][r]);
#undef STAGE_K
#undef STAGE_V
#undef SWZ
#undef PADDR
#undef WRITEBACK
#undef WAITBAR
}

extern "C" void kernel_launch(void* const* d_in, const int* in_sizes, int n_in,
                              void* d_out, int out_size, void* d_ws,
                              size_t ws_size, hipStream_t stream) {
  float* out_o = (float*)d_out;

  const bool sizes_ok =
      (n_in == 12) && in_sizes[0] == 4194304 && in_sizes[1] == 4194304 &&
      in_sizes[2] == 4194304 && in_sizes[3] == 8388608 &&
      in_sizes[4] == 1048576 && in_sizes[5] == 1024 &&
      in_sizes[10] == 1048576 && in_sizes[11] == 1024 &&
      out_size == (2 * 2048 * 1024 + 2 * 16 * 2048 * 2048);
  const size_t WS_NEED = 34603008;  // 4x 8MB bf16 ws + pmask 1MB
  if (!sizes_ok) {
    sentinel_fill<<<dim3(16384), 256, 0, stream>>>(out_o, 555.0f, 4194304);
    return;
  }
  if (ws_size < WS_NEED) {
    sentinel_fill<<<dim3(16384), 256, 0, stream>>>(out_o, 777.0f, 4194304);
    return;
  }

  const float* Q = (const float*)d_in[0];
  const float* K = (const float*)d_in[1];
  const float* V = (const float*)d_in[2];
  const int* mask = (const int*)d_in[3];
  const float* Wq = (const float*)d_in[4];
  const float* bq = (const float*)d_in[5];
  const float* Wk = (const float*)d_in[6];
  const float* bk = (const float*)d_in[7];
  const float* Wv = (const float*)d_in[8];
  const float* bv = (const float*)d_in[9];
  const float* Wo = (const float*)d_in[10];
  const float* bo = (const float*)d_in[11];

  short* qws = (short*)d_ws;               // [2,16,2048,64] bf16
  short* kws = qws + 4194304;              // [2,16,2048,64] bf16
  short* vtws = kws + 4194304;             // [2,16,64,2048] bf16 (v^T)
  short* ctxws = vtws + 4194304;           // [2,2048,1024]  bf16
  u64* pmask = (u64*)(ctxws + 4194304);    // [2,2048,32]    u64

  float* out_attn = out_o + 2 * 2048 * 1024;

  pack_mask<<<dim3(2 * 2048 * 2048 / 256), 256, 0, stream>>>(mask, pmask);
  QkvPtrs p = {Q, K, V, Wq, Wk, Wv, bq, bk, bv, qws, kws, vtws};
  gemm_qkv<<<dim3(32, 8, 3), 256, 0, stream>>>(p);
  attn_fused<<<dim3(32, 32), 256, 0, stream>>>(qws, kws, vtws, pmask,
                                               out_attn, ctxws);
  gemm_out<<<dim3(32, 8), 256, 0, stream>>>(ctxws, Wo, bo, out_o);
}

// Round 14
// 361.766 us; speedup vs baseline: 1.0415x; 1.0415x over previous
//
#include <hip/hip_runtime.h>
#include <stdint.h>

// MultiHeadAttention: B=2, S=2048, D=1024, H=16, dk=64
// d_in (fp32): Q,K,V, mask(int32), Wq,bq,Wk,bk,Wv,bv,Wo,bo
// d_out (FP32): out [2,2048,1024] then attn [2,16,2048,2048], concatenated.
// R14: VALU-cut round. v_cvt_pk_bf16_f32 for all f32->bf16 packing (staging +
//      P-pack), 1/sqrt(dk) folded into Q projection (exact 2^-3), mask bits
//      pre-shifted to u32. Structure identical to R13.

typedef __attribute__((ext_vector_type(8))) short bf16x8;
typedef __attribute__((ext_vector_type(4))) float f32x4;
typedef unsigned long long u64;

#define MFMA16(a, b, c) __builtin_amdgcn_mfma_f32_16x16x32_bf16((a), (b), (c), 0, 0, 0)

#define GLDS16(g, l)                                                   \
  __builtin_amdgcn_global_load_lds(                                    \
      (const __attribute__((address_space(1))) unsigned int*)(g),      \
      (__attribute__((address_space(3))) unsigned int*)(l), 16, 0, 0)

__device__ __forceinline__ float bf2f(short s) {
  union { float f; unsigned u; } x;
  x.u = ((unsigned)(unsigned short)s) << 16;
  return x.f;
}
__device__ __forceinline__ short f2bf(float f) {  // RTNE (epilogue singles)
  union { float f; unsigned u; } x;
  x.f = f;
  unsigned r = x.u + 0x7fffu + ((x.u >> 16) & 1u);
  return (short)(r >> 16);
}
// hw packed cvt: lo -> bits[15:0], hi -> bits[31:16]
__device__ __forceinline__ unsigned cvtpk2(float lo, float hi) {
  unsigned r;
  asm("v_cvt_pk_bf16_f32 %0, %1, %2" : "=v"(r) : "v"(lo), "v"(hi));
  return r;
}
__device__ __forceinline__ bf16x8 pack8(float4 a, float4 b) {
  union { unsigned u[4]; bf16x8 v; } x;
  x.u[0] = cvtpk2(a.x, a.y);
  x.u[1] = cvtpk2(a.z, a.w);
  x.u[2] = cvtpk2(b.x, b.y);
  x.u[3] = cvtpk2(b.z, b.w);
  return x.v;
}

// ---------------- diagnostic sentinel --------------------------------------
__global__ __launch_bounds__(256) void sentinel_fill(float* __restrict__ out,
                                                     float v, int n) {
  int i = blockIdx.x * 256 + threadIdx.x;
  if (i < n) out[i] = v;
}

// ---------------- mask bit-pack: [B,S,S] int32 -> [B,S,S/64] u64 ----------
__global__ __launch_bounds__(256) void pack_mask(const int* __restrict__ m,
                                                 u64* __restrict__ p) {
  long idx = (long)blockIdx.x * 256 + threadIdx.x;
  u64 b = __ballot(m[idx] != 0);
  if ((threadIdx.x & 63) == 0) p[idx >> 6] = b;
}

// ------------- merged QKV projection: 3 GEMMs in one launch ----------------
// z==0 epilogue folds the attention 1/sqrt(dk)=0.125 scale into q (exact).
struct QkvPtrs {
  const float *A0, *A1, *A2;
  const float *W0, *W1, *W2;
  const float *c0, *c1, *c2;
  short *o0, *o1, *o2;
};
__global__ __launch_bounds__(256) void gemm_qkv(QkvPtrs p) {
  __shared__ short As[128 * 32];
  __shared__ short Bs[128 * 32];
  const int z = blockIdx.z;
  const float* Af = z == 0 ? p.A0 : (z == 1 ? p.A1 : p.A2);
  const float* W = z == 0 ? p.W0 : (z == 1 ? p.W1 : p.W2);
  const float* bias = z == 0 ? p.c0 : (z == 1 ? p.c1 : p.c2);
  short* outs = z == 0 ? p.o0 : (z == 1 ? p.o1 : p.o2);

  const int tid = threadIdx.x;
  const int lane = tid & 63;
  const int wid = tid >> 6;
  const int wr = wid >> 1, wc = wid & 1;
  const int m0 = blockIdx.x * 128;
  const int n0 = blockIdx.y * 128;

  const int srow = tid >> 1;
  const int scol = (tid & 1) << 4;
  const long aoff = (long)(m0 + srow) * 1024 + scol;
  const float* Wg = W + (long)(n0 + srow) * 1024 + scol;
  short* sA = As + srow * 32 + scol;
  short* sB = Bs + srow * 32 + scol;

  f32x4 acc[4][4] = {};
  const int fr = lane & 15;
  const int fc = (lane >> 4) << 3;

  for (int k0 = 0; k0 < 1024; k0 += 32) {
    __syncthreads();
    float4 x0 = *(const float4*)(Af + aoff + k0);
    float4 x1 = *(const float4*)(Af + aoff + k0 + 4);
    float4 x2 = *(const float4*)(Af + aoff + k0 + 8);
    float4 x3 = *(const float4*)(Af + aoff + k0 + 12);
    float4 w0 = *(const float4*)(Wg + k0);
    float4 w1 = *(const float4*)(Wg + k0 + 4);
    float4 w2 = *(const float4*)(Wg + k0 + 8);
    float4 w3 = *(const float4*)(Wg + k0 + 12);
    *(bf16x8*)sA = pack8(x0, x1);
    *(bf16x8*)(sA + 8) = pack8(x2, x3);
    *(bf16x8*)sB = pack8(w0, w1);
    *(bf16x8*)(sB + 8) = pack8(w2, w3);
    __syncthreads();
    bf16x8 a[4], b[4];
#pragma unroll
    for (int i = 0; i < 4; ++i)
      a[i] = *(const bf16x8*)&As[(wr * 64 + i * 16 + fr) * 32 + fc];
#pragma unroll
    for (int i = 0; i < 4; ++i)
      b[i] = *(const bf16x8*)&Bs[(wc * 64 + i * 16 + fr) * 32 + fc];
#pragma unroll
    for (int i = 0; i < 4; ++i)
#pragma unroll
      for (int j = 0; j < 4; ++j)
        acc[i][j] = MFMA16(a[i], b[j], acc[i][j]);
  }

#pragma unroll
  for (int i = 0; i < 4; ++i) {
    const int row0 = m0 + wr * 64 + i * 16 + (lane >> 4) * 4;
#pragma unroll
    for (int j = 0; j < 4; ++j) {
      const int col = n0 + wc * 64 + j * 16 + fr;
      const float bv = bias[col];
      const int h = col >> 6, dd = col & 63;
      if (z != 2) {
#pragma unroll
        for (int r = 0; r < 4; ++r) {
          const int m = row0 + r;
          float val = acc[i][j][r] + bv;
          if (z == 0) val *= 0.125f;  // fold 1/sqrt(dk) into q (exact 2^-3)
          const long o = (((long)(m >> 11) * 16 + h) * 2048 + (m & 2047)) * 64 + dd;
          outs[o] = f2bf(val);
        }
      } else {
        const long o = (((long)(row0 >> 11) * 16 + h) * 64 + dd) * 2048 + (row0 & 2047);
        union { unsigned short us[4]; uint2 v; } pk;
#pragma unroll
        for (int r = 0; r < 4; ++r) pk.us[r] = (unsigned short)f2bf(acc[i][j][r] + bv);
        *(uint2*)&outs[o] = pk.v;
      }
    }
  }
}

// ---------------- final GEMM: out = ctx(bf16) @ Wo^T + bo (fp32 out) -------
__global__ __launch_bounds__(256) void gemm_out(const short* __restrict__ Ab,
                                                const float* __restrict__ W,
                                                const float* __restrict__ bias,
                                                float* __restrict__ outf) {
  __shared__ short As[128 * 32];
  __shared__ short Bs[128 * 32];
  const int tid = threadIdx.x;
  const int lane = tid & 63;
  const int wid = tid >> 6;
  const int wr = wid >> 1, wc = wid & 1;
  const int m0 = blockIdx.x * 128;
  const int n0 = blockIdx.y * 128;

  const int srow = tid >> 1;
  const int scol = (tid & 1) << 4;
  const long aoff = (long)(m0 + srow) * 1024 + scol;
  const float* Wg = W + (long)(n0 + srow) * 1024 + scol;
  short* sA = As + srow * 32 + scol;
  short* sB = Bs + srow * 32 + scol;

  f32x4 acc[4][4] = {};
  const int fr = lane & 15;
  const int fc = (lane >> 4) << 3;

  for (int k0 = 0; k0 < 1024; k0 += 32) {
    __syncthreads();
    bf16x8 va0 = *(const bf16x8*)(Ab + aoff + k0);
    bf16x8 va1 = *(const bf16x8*)(Ab + aoff + k0 + 8);
    float4 w0 = *(const float4*)(Wg + k0);
    float4 w1 = *(const float4*)(Wg + k0 + 4);
    float4 w2 = *(const float4*)(Wg + k0 + 8);
    float4 w3 = *(const float4*)(Wg + k0 + 12);
    *(bf16x8*)sA = va0;
    *(bf16x8*)(sA + 8) = va1;
    *(bf16x8*)sB = pack8(w0, w1);
    *(bf16x8*)(sB + 8) = pack8(w2, w3);
    __syncthreads();
    bf16x8 a[4], b[4];
#pragma unroll
    for (int i = 0; i < 4; ++i)
      a[i] = *(const bf16x8*)&As[(wr * 64 + i * 16 + fr) * 32 + fc];
#pragma unroll
    for (int i = 0; i < 4; ++i)
      b[i] = *(const bf16x8*)&Bs[(wc * 64 + i * 16 + fr) * 32 + fc];
#pragma unroll
    for (int i = 0; i < 4; ++i)
#pragma unroll
      for (int j = 0; j < 4; ++j)
        acc[i][j] = MFMA16(a[i], b[j], acc[i][j]);
  }

#pragma unroll
  for (int i = 0; i < 4; ++i) {
    const int row0 = m0 + wr * 64 + i * 16 + (lane >> 4) * 4;
#pragma unroll
    for (int j = 0; j < 4; ++j) {
      const int col = n0 + wc * 64 + j * 16 + fr;
      const float bv = bias[col];
#pragma unroll
      for (int r = 0; r < 4; ++r)
        outf[(long)(row0 + r) * 1024 + col] = acc[i][j][r] + bv;
    }
  }
}

// ------------- fused attention: counted-vmcnt pipeline -----------------------
// 16 q-rows/wave, 64 rows/block; grid (32 bh, 32 qt); LDS 40KB, 4 blocks/CU.
// q pre-scaled by 0.125 => no per-score mul. Mask pre-shifted to u32 nibble.
__global__ __launch_bounds__(256) void attn_fused(
    const short* __restrict__ qw, const short* __restrict__ kw,
    const short* __restrict__ vtw, const u64* __restrict__ pm,
    float* __restrict__ attn, short* __restrict__ ctx) {
  __shared__ short Ks[2][4096];   // [64 k][64 d] bf16, swizzled
  __shared__ short Vs[2][4096];   // [64 d][64 k] bf16, swizzled
  __shared__ short P[4][1024];    // per-wave [16 r][64 c], XOR-swizzled
  const int tid = threadIdx.x;
  const int lane = tid & 63;
  const int wid = tid >> 6;
  const int bh = blockIdx.x;
  const int mb = bh & 1;  // torch tile quirk: mask batch = (b*H+h)%B
  const int q0 = blockIdx.y * 64 + wid * 16;
  const int fr = lane & 15;
  const int fg = lane >> 4;
  short* Pw = P[wid];

  bf16x8 aq[2];
  {
    const short* qb = qw + ((long)bh * 2048 + q0 + fr) * 64 + fg * 8;
    aq[0] = *(const bf16x8*)qb;
    aq[1] = *(const bf16x8*)(qb + 32);
  }

  const u64* mbase = pm + ((long)mb * 2048 + q0) * 32;
  const short* kbase = kw + (long)bh * 2048 * 64;
  const short* vbase = vtw + (long)bh * 64 * 2048;
  const long arow = (long)bh * 2048 + q0;

  const int sidx0 = tid;
  const int sidx1 = 256 + tid;
  const int sr0 = sidx0 >> 3, ss0 = (sidx0 ^ sr0) & 7;
  const int sr1 = sidx1 >> 3, ss1 = (sidx1 ^ sr1) & 7;
  short* ldst0 = &Ks[0][0] + (long)(wid * 64) * 8;
  short* ldst1 = &Ks[0][0] + (long)(256 + wid * 64) * 8;
  const long kofs = (long)(&Vs[0][0] - &Ks[0][0]);

#define STAGE_K(buf, kt)                                              \
  {                                                                   \
    const short* s_ = kbase + (long)((kt) * 64) * 64;                 \
    GLDS16(s_ + sr0 * 64 + ss0 * 8, ldst0 + (buf) * 4096);            \
    GLDS16(s_ + sr1 * 64 + ss1 * 8, ldst1 + (buf) * 4096);            \
  }
#define STAGE_V(buf, kt)                                              \
  {                                                                   \
    const short* s_ = vbase + (kt) * 64;                              \
    GLDS16(s_ + (long)sr0 * 2048 + ss0 * 8, ldst0 + kofs + (buf) * 4096); \
    GLDS16(s_ + (long)sr1 * 2048 + ss1 * 8, ldst1 + kofs + (buf) * 4096); \
  }
#define SWZ(row, slot) (((row) << 6) + ((((slot) ^ ((row) & 7))) << 3))
#define PADDR(row, col) \
  (((row) << 6) + (((((col) >> 3) ^ ((row) & 7))) << 3) + ((col) & 7))
#define WRITEBACK(kt)                                                 \
  {                                                                   \
    _Pragma("unroll") for (int c = 0; c < 4; ++c) {                   \
      const int idx = c * 64 + lane;                                  \
      const int row = idx >> 4;                                       \
      const int col = (idx & 15) * 4;                                 \
      union { uint2 w; short s[4]; } v4;                              \
      v4.w = *(const uint2*)&Pw[PADDR(row, col)];                     \
      float4 f;                                                       \
      f.x = bf2f(v4.s[0]); f.y = bf2f(v4.s[1]);                       \
      f.z = bf2f(v4.s[2]); f.w = bf2f(v4.s[3]);                       \
      *(float4*)&attn[(arow + row) * 2048 + (kt) * 64 + col] = f;     \
    }                                                                 \
  }
#define WAITBAR(N)                                                    \
  {                                                                   \
    asm volatile("s_waitcnt vmcnt(" #N ")" ::: "memory");             \
    __builtin_amdgcn_sched_barrier(0);                                \
    __builtin_amdgcn_s_barrier();                                     \
    __builtin_amdgcn_sched_barrier(0);                                \
  }

  // ---- phase 1: denominator (swapped QK^T; lane owns q-row q0+fr) ---------
  float rs = 0.f;
  STAGE_K(0, 0);
  u64 mrow = mbase[fr * 32 + 0];
  WAITBAR(1)
  int cur = 0;
  for (int kt = 0; kt < 32; ++kt) {
    u64 mrow_next = 0;
    if (kt < 31) {
      STAGE_K(cur ^ 1, kt + 1);
      mrow_next = mbase[fr * 32 + kt + 1];
    }
#pragma unroll
    for (int ni = 0; ni < 4; ++ni) {
      const int R = ni * 16 + fr;
      bf16x8 b0 = *(const bf16x8*)&Ks[cur][SWZ(R, fg)];
      bf16x8 b1 = *(const bf16x8*)&Ks[cur][SWZ(R, 4 + fg)];
      const int kb0 = ni * 16 + fg * 4;
      const unsigned m4 = (unsigned)(mrow >> kb0) & 0xFu;
      f32x4 s = {0.f, 0.f, 0.f, 0.f};
      s = MFMA16(b0, aq[0], s);
      s = MFMA16(b1, aq[1], s);
#pragma unroll
      for (int r = 0; r < 4; ++r)
        if ((m4 >> r) & 1u) rs += __expf(s[r]);
    }
    if (kt < 31) {
      WAITBAR(1)
      cur ^= 1;
      mrow = mrow_next;
    }
  }
  float il;
  {
    float v = rs;
    v += __shfl_xor(v, 16);
    v += __shfl_xor(v, 32);
    il = 1.0f / v;
  }
  __builtin_amdgcn_s_barrier();  // all waves done with phase-1 buffers

  // ---- phase 2: p -> attn + ctx += P@V (counted-vmcnt pipeline) -----------
  f32x4 cacc[4] = {};
  STAGE_K(0, 0);
  STAGE_V(0, 0);
  mrow = mbase[fr * 32 + 0];
  WAITBAR(1)
  cur = 0;
  for (int kt = 0; kt < 32; ++kt) {
    u64 mrow_next = 0;
    if (kt < 31) {
      STAGE_K(cur ^ 1, kt + 1);
      STAGE_V(cur ^ 1, kt + 1);
      mrow_next = mbase[fr * 32 + kt + 1];
    }

#pragma unroll
    for (int ni = 0; ni < 4; ++ni) {
      const int R = ni * 16 + fr;
      bf16x8 b0 = *(const bf16x8*)&Ks[cur][SWZ(R, fg)];
      bf16x8 b1 = *(const bf16x8*)&Ks[cur][SWZ(R, 4 + fg)];
      const int kb0 = ni * 16 + fg * 4;
      const unsigned m4 = (unsigned)(mrow >> kb0) & 0xFu;
      f32x4 s = {0.f, 0.f, 0.f, 0.f};
      s = MFMA16(b0, aq[0], s);
      s = MFMA16(b1, aq[1], s);
      float p0 = (m4 & 1u) ? __expf(s[0]) * il : 0.0f;
      float p1 = (m4 & 2u) ? __expf(s[1]) * il : 0.0f;
      float p2 = (m4 & 4u) ? __expf(s[2]) * il : 0.0f;
      float p3 = (m4 & 8u) ? __expf(s[3]) * il : 0.0f;
      uint2 pk;
      pk.x = cvtpk2(p0, p1);
      pk.y = cvtpk2(p2, p3);
      *(uint2*)&Pw[PADDR(fr, kb0)] = pk;
    }

    // ctx += P(16x64) @ V(64x64)   (same-wave LDS dep; ds ops in-order)
#pragma unroll
    for (int ks = 0; ks < 2; ++ks) {
      bf16x8 pa = *(const bf16x8*)&Pw[PADDR(fr, ks * 32 + fg * 8)];
#pragma unroll
      for (int ni = 0; ni < 4; ++ni) {
        const int R = ni * 16 + fr;
        bf16x8 bv = *(const bf16x8*)&Vs[cur][SWZ(R, ks * 4 + fg)];
        cacc[ni] = MFMA16(pa, bv, cacc[ni]);
      }
    }

    WRITEBACK(kt);  // stores issue late; allowed to stay in flight

    if (kt < 31) {
      WAITBAR(5)  // stage retired; mask + stores in flight
      cur ^= 1;
      mrow = mrow_next;
    }
  }

  // ctx: [B,S,D] row-major (bf16) for the final GEMM
  const int b_ = bh >> 4, h_ = bh & 15;
#pragma unroll
  for (int ni = 0; ni < 4; ++ni)
#pragma unroll
    for (int r = 0; r < 4; ++r)
      ctx[((long)b_ * 2048 + q0 + fg * 4 + r) * 1024 + h_ * 64 + ni * 16 + fr] =
          f2bf(cacc[ni][r]);
#undef STAGE_K
#undef STAGE_V
#undef SWZ
#undef PADDR
#undef WRITEBACK
#undef WAITBAR
}

extern "C" void kernel_launch(void* const* d_in, const int* in_sizes, int n_in,
                              void* d_out, int out_size, void* d_ws,
                              size_t ws_size, hipStream_t stream) {
  float* out_o = (float*)d_out;

  const bool sizes_ok =
      (n_in == 12) && in_sizes[0] == 4194304 && in_sizes[1] == 4194304 &&
      in_sizes[2] == 4194304 && in_sizes[3] == 8388608 &&
      in_sizes[4] == 1048576 && in_sizes[5] == 1024 &&
      in_sizes[10] == 1048576 && in_sizes[11] == 1024 &&
      out_size == (2 * 2048 * 1024 + 2 * 16 * 2048 * 2048);
  const size_t WS_NEED = 34603008;  // 4x 8MB bf16 ws + pmask 1MB
  if (!sizes_ok) {
    sentinel_fill<<<dim3(16384), 256, 0, stream>>>(out_o, 555.0f, 4194304);
    return;
  }
  if (ws_size < WS_NEED) {
    sentinel_fill<<<dim3(16384), 256, 0, stream>>>(out_o, 777.0f, 4194304);
    return;
  }

  const float* Q = (const float*)d_in[0];
  const float* K = (const float*)d_in[1];
  const float* V = (const float*)d_in[2];
  const int* mask = (const int*)d_in[3];
  const float* Wq = (const float*)d_in[4];
  const float* bq = (const float*)d_in[5];
  const float* Wk = (const float*)d_in[6];
  const float* bk = (const float*)d_in[7];
  const float* Wv = (const float*)d_in[8];
  const float* bv = (const float*)d_in[9];
  const float* Wo = (const float*)d_in[10];
  const float* bo = (const float*)d_in[11];

  short* qws = (short*)d_ws;               // [2,16,2048,64] bf16 (pre-scaled)
  short* kws = qws + 4194304;              // [2,16,2048,64] bf16
  short* vtws = kws + 4194304;             // [2,16,64,2048] bf16 (v^T)
  short* ctxws = vtws + 4194304;           // [2,2048,1024]  bf16
  u64* pmask = (u64*)(ctxws + 4194304);    // [2,2048,32]    u64

  float* out_attn = out_o + 2 * 2048 * 1024;

  pack_mask<<<dim3(2 * 2048 * 2048 / 256), 256, 0, stream>>>(mask, pmask);
  QkvPtrs p = {Q, K, V, Wq, Wk, Wv, bq, bk, bv, qws, kws, vtws};
  gemm_qkv<<<dim3(32, 8, 3), 256, 0, stream>>>(p);
  attn_fused<<<dim3(32, 32), 256, 0, stream>>>(qws, kws, vtws, pmask,
                                               out_attn, ctxws);
  gemm_out<<<dim3(32, 8), 256, 0, stream>>>(ctxws, Wo, bo, out_o);
}